// Round 6
// baseline (98.099 us; speedup 1.0000x reference)
//
#include <hip/hip_runtime.h>
#include <math.h>

#define NBATCH 16
#define NANCH  3
#define NHH    64
#define NWW    64
#define NTT    50
#define NCLS   80
#define HW     (NHH*NWW)          // 4096
#define CELLS  (NBATCH*NANCH*HW)  // 196608
#define VEC    4                  // cells per thread
#define CELLBLOCKS (CELLS/(256*VEC))   // 192
#define TPB    13                 // target blocks per batch (4 waves/block -> 52 >= 50)
#define TBLOCKS (NBATCH*TPB)      // 208
#define NPART  (TBLOCKS + CELLBLOCKS)  // 400 partials

// anchors / stride
#define AW0 1.875f
#define AW1 3.875f
#define AW2 3.6875f
#define AH0 3.8125f
#define AH1 2.8125f
#define AH2 7.4375f

// Wave-0-only target prep: one coalesced load + ballot-based cumprod validity.
__device__ __forceinline__ void prep_targets(const float* __restrict__ target, int b, int tid,
                                             float* s_gx, float* s_gy, float* s_gw, float* s_gh,
                                             float4* s_box, float2* s_gam, int* s_meta) {
    // caller guarantees tid < 64 (wave 0)
    const float* tb0 = target + b * (NTT * 5);
    float c1 = 0.f, c2 = 0.f, c3 = 0.f, c4 = 0.f;
    bool nz = false;
    if (tid < NTT) {
        c1 = tb0[tid * 5 + 1]; c2 = tb0[tid * 5 + 2];
        c3 = tb0[tid * 5 + 3]; c4 = tb0[tid * 5 + 4];
        nz = (c1 != 0.0f);
    }
    const unsigned long long mask = __ballot(nz);
    const int first_zero = __ffsll((unsigned long long)~mask) - 1;  // cumprod boundary
    if (tid < NTT) {
        const bool valid = tid < first_zero;
        const float gx = c1 * NWW, gy = c2 * NHH;
        const float gw = c3 * NWW, gh = c4 * NHH;

        // best anchor (first max wins)
        const float ga = gw * gh;
        const float i0 = fminf(gw, AW0) * fminf(gh, AH0);
        const float i1 = fminf(gw, AW1) * fminf(gh, AH1);
        const float i2 = fminf(gw, AW2) * fminf(gh, AH2);
        const float r0 = i0 / (ga + AW0 * AH0 - i0);
        const float r1 = i1 / (ga + AW1 * AH1 - i1);
        const float r2 = i2 / (ga + AW2 * AH2 - i2);
        int best = 0; float bv = r0;
        if (r1 > bv) { bv = r1; best = 1; }
        if (r2 > bv) { bv = r2; best = 2; }

        int gi = (int)floorf(gx); gi = gi < 0 ? 0 : (gi > NWW - 1 ? NWW - 1 : gi);
        int gj = (int)floorf(gy); gj = gj < 0 ? 0 : (gj > NHH - 1 ? NHH - 1 : gj);

        const int m = valid ? ((1 << 15) | (best << 12) | (gj << 6) | gi) : 0;
        s_gx[tid] = gx; s_gy[tid] = gy; s_gw[tid] = gw; s_gh[tid] = gh;
        s_box[tid] = make_float4(gx - gw * 0.5f, gx + gw * 0.5f,
                                 gy - gh * 0.5f, gy + gh * 0.5f);
        s_gam[tid] = make_float2(ga, __int_as_float(m));
        s_meta[tid] = m;
    }
}

__global__ __launch_bounds__(256) void yolo_loss_kernel(
    const float* __restrict__ out,     // (16, 255, 64, 64)
    const float* __restrict__ target,  // (16, 250)
    float* __restrict__ partials)      // NPART slots in d_ws
{
    __shared__ float  s_gx[NTT], s_gy[NTT], s_gw[NTT], s_gh[NTT];
    __shared__ float4 s_box[NTT];
    __shared__ float2 s_gam[NTT];
    __shared__ int    s_meta[NTT];
    __shared__ float  s_part[4];

    const int tid  = threadIdx.x;
    const int lane = tid & 63, wid = tid >> 6;

    if (blockIdx.x < TBLOCKS) {
        // ============ target blocks: one wave per (b,t), class NLL ============
        const int tb = blockIdx.x;
        const int b  = tb / TPB;
        const int t  = (tb % TPB) * 4 + wid;

        if (tid < 64)
            prep_targets(target, b, tid, s_gx, s_gy, s_gw, s_gh, s_box, s_gam, s_meta);
        __syncthreads();

        float nll = 0.0f;   // lane-0 of each wave holds this wave's contribution
        if (t < NTT) {
            const int m = s_meta[t];            // wave-uniform
            if (m != 0) {
                // "last valid t wins": skip if any later t has the same cell key
                const int mv_lane = (lane < NTT) ? s_meta[lane] : 0;
                const unsigned long long dup = __ballot(lane > t && mv_lane == m);
                if (dup == 0ULL) {
                    const int best = (m >> 12) & 3;
                    const int hw   = m & 0xFFF;
                    const float* cb = out + ((size_t)(b * NANCH + best) * (5 + NCLS) + 5) * HW + hw;

                    const float l0 = cb[lane * HW];
                    const float l1 = (lane < NCLS - 64) ? cb[(lane + 64) * HW] : -INFINITY;

                    float mx = fmaxf(l0, l1);
                    #pragma unroll
                    for (int off = 32; off > 0; off >>= 1)
                        mx = fmaxf(mx, __shfl_xor(mx, off, 64));

                    float e = __expf(l0 - mx) + ((lane < NCLS - 64) ? __expf(l1 - mx) : 0.0f);
                    #pragma unroll
                    for (int off = 32; off > 0; off >>= 1)
                        e += __shfl_xor(e, off, 64);

                    if (lane == 0) {
                        const int tc = (int)target[b * (NTT * 5) + t * 5];
                        const float lt = cb[tc * HW];
                        nll = -(lt - mx - __logf(e));
                    }
                }
            }
        }
        if (lane == 0) s_part[wid] = nll;
        __syncthreads();
        if (tid == 0)
            partials[blockIdx.x] = s_part[0] + s_part[1] + s_part[2] + s_part[3];
        return;
    }

    // ============ cell blocks: VEC=4 cells per thread via float4 ============
    const int cblk = blockIdx.x - TBLOCKS;          // 0..191
    const int b    = cblk / (CELLBLOCKS / NBATCH);  // /12
    const int rem  = (cblk % 12) * 1024 + tid * VEC; // index within (a,hw) space of batch b
    const int a    = rem >> 12;                      // /4096
    const int hw   = rem & 4095;
    const int h    = hw >> 6;
    const int w    = hw & 63;                        // multiple of 4; w+3 <= 63, no row straddle

    // 5 coalesced float4 loads (16B/lane), issued before the prep barrier
    const float* base = out + ((size_t)(b * NANCH + a) * (5 + NCLS)) * HW + hw;
    const float4 r0v = *(const float4*)(base);
    const float4 r1v = *(const float4*)(base + HW);
    const float4 r2v = *(const float4*)(base + 2 * HW);
    const float4 r3v = *(const float4*)(base + 3 * HW);
    const float4 r4v = *(const float4*)(base + 4 * HW);

    if (tid < 64)
        prep_targets(target, b, tid, s_gx, s_gy, s_gw, s_gh, s_box, s_gam, s_meta);
    __syncthreads();

    // reference's anchor-broadcast quirk: effective anchor = (3b+a)//16 (block-uniform)
    const int aidx = (3 * b + a) >> 4;
    const float aw = aidx == 0 ? AW0 : (aidx == 1 ? AW1 : AW2);
    const float ah = aidx == 0 ? AH0 : (aidx == 1 ? AH1 : AH2);

    const float r0a[VEC] = {r0v.x, r0v.y, r0v.z, r0v.w};
    const float r1a[VEC] = {r1v.x, r1v.y, r1v.z, r1v.w};
    const float r2a[VEC] = {r2v.x, r2v.y, r2v.z, r2v.w};
    const float r3a[VEC] = {r3v.x, r3v.y, r3v.z, r3v.w};
    const float r4a[VEC] = {r4v.x, r4v.y, r4v.z, r4v.w};

    float sx[VEC], sy[VEC], pw[VEC], ph[VEC], parea[VEC];
    float hx0[VEC], hx1[VEC], hy0[VEC], hy1[VEC];
    float curmax[VEC];
    int   tlast[VEC];
    #pragma unroll
    for (int j = 0; j < VEC; ++j) {
        sx[j] = __builtin_amdgcn_rcpf(1.0f + __expf(-r0a[j]));
        sy[j] = __builtin_amdgcn_rcpf(1.0f + __expf(-r1a[j]));
        const float px = sx[j] + (float)(w + j);
        const float py = sy[j] + (float)h;
        pw[j] = __expf(r2a[j]) * aw;
        ph[j] = __expf(r3a[j]) * ah;
        parea[j] = pw[j] * ph[j];
        hx0[j] = px - pw[j] * 0.5f; hx1[j] = px + pw[j] * 0.5f;
        hy0[j] = py - ph[j] * 0.5f; hy1[j] = py + ph[j] * 0.5f;
        curmax[j] = 0.0f;
        tlast[j]  = -1;
    }

    const int key0 = (1 << 15) | (a << 12) | (h << 6) | w;   // cell j's key = key0 + j

    #pragma unroll 2
    for (int t = 0; t < NTT; ++t) {
        const float4 bx  = s_box[t];
        const float2 gam = s_gam[t];
        const int    m   = __float_as_int(gam.y);
        #pragma unroll
        for (int j = 0; j < VEC; ++j) {
            // intersection extents: min(hi) - max(lo)
            const float cw = fminf(hx1[j], bx.y) - fmaxf(hx0[j], bx.x);
            const float ch = fminf(hy1[j], bx.w) - fmaxf(hy0[j], bx.z);
            const float carea = (cw <= 0.0f || ch <= 0.0f) ? 0.0f : cw * ch;
            const float uarea = parea[j] + gam.x - carea;
            const float iou   = carea * __builtin_amdgcn_rcpf(uarea);
            curmax[j] = fmaxf(curmax[j], (m != 0) ? iou : 0.0f);
            if (m == key0 + j) tlast[j] = t;  // key has valid bit set; last valid t wins
        }
    }

    float lsum = 0.0f;
    #pragma unroll
    for (int j = 0; j < VEC; ++j) {
        const float conf = __builtin_amdgcn_rcpf(1.0f + __expf(-r4a[j]));
        if (tlast[j] >= 0) {
            const int tl   = tlast[j];
            const int best = (s_meta[tl] >> 12) & 3;
            const float baw = best == 0 ? AW0 : (best == 1 ? AW1 : AW2);
            const float bah = best == 0 ? AH0 : (best == 1 ? AH1 : AH2);
            const float tx = s_gx[tl] - (float)(w + j);
            const float ty = s_gy[tl] - (float)h;
            const float tw = __logf(s_gw[tl] * __builtin_amdgcn_rcpf(baw));
            const float th = __logf(s_gh[tl] * __builtin_amdgcn_rcpf(bah));
            const float dx = sx[j] - tx, dy = sy[j] - ty;
            const float dw = r2a[j] - tw, dh = r3a[j] - th;
            const float dc = conf - 1.0f;
            lsum += dc * dc + 0.5f * (dx * dx + dy * dy + dw * dw + dh * dh);
        } else {
            lsum += (curmax[j] > 0.5f) ? 0.0f : conf * conf;
        }
    }

    // reduce: wave shuffle -> LDS -> one partial store per block (no atomics)
    float v = lsum;
    #pragma unroll
    for (int off = 32; off > 0; off >>= 1) v += __shfl_down(v, off, 64);
    if (lane == 0) s_part[wid] = v;
    __syncthreads();
    if (tid == 0)
        partials[blockIdx.x] = s_part[0] + s_part[1] + s_part[2] + s_part[3];
}

__global__ __launch_bounds__(64) void yolo_reduce_kernel(
    const float* __restrict__ partials, float* __restrict__ loss)
{
    const int tid = threadIdx.x;   // single wave, no LDS / no barrier
    float v = 0.0f;
    #pragma unroll
    for (int i = tid; i < NPART; i += 64) v += partials[i];
    #pragma unroll
    for (int off = 32; off > 0; off >>= 1) v += __shfl_down(v, off, 64);
    if (tid == 0) loss[0] = v;
}

extern "C" void kernel_launch(void* const* d_in, const int* in_sizes, int n_in,
                              void* d_out, int out_size, void* d_ws, size_t ws_size,
                              hipStream_t stream) {
    const float* out_t  = (const float*)d_in[0];   // (16, 255, 64, 64) f32
    const float* target = (const float*)d_in[1];   // (16, 250) f32
    float* loss     = (float*)d_out;
    float* partials = (float*)d_ws;

    yolo_loss_kernel<<<NPART, 256, 0, stream>>>(out_t, target, partials);
    yolo_reduce_kernel<<<1, 64, 0, stream>>>(partials, loss);
}

// Round 7
// 94.240 us; speedup vs baseline: 1.0409x; 1.0409x over previous
//
#include <hip/hip_runtime.h>
#include <math.h>

#define NBATCH 16
#define NANCH  3
#define NHH    64
#define NWW    64
#define NTT    50
#define NCLS   80
#define HW     (NHH*NWW)          // 4096
#define CELLS  (NBATCH*NANCH*HW)  // 196608
#define CELLBLOCKS (CELLS/256)    // 768 (48 per batch)
#define NPART  CELLBLOCKS         // 768 partials

// anchors / stride
#define AW0 1.875f
#define AW1 3.875f
#define AW2 3.6875f
#define AH0 3.8125f
#define AH1 2.8125f
#define AH2 7.4375f

// Wave-0-only target prep: one coalesced load + ballot-based cumprod validity.
// Invalid targets get an (+inf,-inf,...) box so the IoU loop needs no validity test.
__device__ __forceinline__ void prep_targets(const float* __restrict__ target, int b, int tid,
                                             float* s_gx, float* s_gy, float* s_gw, float* s_gh,
                                             float4* s_box, float2* s_gam, int* s_meta) {
    // caller guarantees tid < 64 (wave 0)
    const float* tb0 = target + b * (NTT * 5);
    float c1 = 0.f, c2 = 0.f, c3 = 0.f, c4 = 0.f;
    bool nz = false;
    if (tid < NTT) {
        c1 = tb0[tid * 5 + 1]; c2 = tb0[tid * 5 + 2];
        c3 = tb0[tid * 5 + 3]; c4 = tb0[tid * 5 + 4];
        nz = (c1 != 0.0f);
    }
    const unsigned long long mask = __ballot(nz);
    const int first_zero = __ffsll((unsigned long long)~mask) - 1;  // cumprod boundary
    if (tid < NTT) {
        const bool valid = tid < first_zero;
        const float gx = c1 * NWW, gy = c2 * NHH;
        const float gw = c3 * NWW, gh = c4 * NHH;

        // best anchor (first max wins)
        const float ga = gw * gh;
        const float i0 = fminf(gw, AW0) * fminf(gh, AH0);
        const float i1 = fminf(gw, AW1) * fminf(gh, AH1);
        const float i2 = fminf(gw, AW2) * fminf(gh, AH2);
        const float r0 = i0 / (ga + AW0 * AH0 - i0);
        const float r1 = i1 / (ga + AW1 * AH1 - i1);
        const float r2 = i2 / (ga + AW2 * AH2 - i2);
        int best = 0; float bv = r0;
        if (r1 > bv) { bv = r1; best = 1; }
        if (r2 > bv) { bv = r2; best = 2; }

        int gi = (int)floorf(gx); gi = gi < 0 ? 0 : (gi > NWW - 1 ? NWW - 1 : gi);
        int gj = (int)floorf(gy); gj = gj < 0 ? 0 : (gj > NHH - 1 ? NHH - 1 : gj);

        const int m = valid ? ((1 << 15) | (best << 12) | (gj << 6) | gi) : 0;
        const float inf = __int_as_float(0x7f800000);
        s_gx[tid] = gx; s_gy[tid] = gy; s_gw[tid] = gw; s_gh[tid] = gh;
        s_box[tid] = valid ? make_float4(gx - gw * 0.5f, gx + gw * 0.5f,
                                         gy - gh * 0.5f, gy + gh * 0.5f)
                           : make_float4(inf, -inf, inf, -inf);  // forces carea=0
        s_gam[tid] = make_float2(ga, __int_as_float(m));
        s_meta[tid] = m;
    }
}

__global__ __launch_bounds__(256) void yolo_loss_kernel(
    const float* __restrict__ out,     // (16, 255, 64, 64)
    const float* __restrict__ target,  // (16, 250)
    float* __restrict__ partials)      // NPART slots in d_ws
{
    __shared__ float  s_gx[NTT], s_gy[NTT], s_gw[NTT], s_gh[NTT];
    __shared__ float4 s_box[NTT];
    __shared__ float2 s_gam[NTT];
    __shared__ int    s_meta[NTT];
    __shared__ float  s_part[4];

    const int tid  = threadIdx.x;
    const int lane = tid & 63, wid = tid >> 6;

    const int cblk = blockIdx.x;          // 0..767
    const int b    = cblk / 48;
    const int sub  = cblk % 48;

    const int cell = cblk * 256 + tid;
    const int rem  = cell % (NANCH * HW);
    const int a    = rem / HW;
    const int hw   = rem % HW;
    const int h    = hw >> 6;
    const int w    = hw & 63;

    // issue the 5 strided cell loads before the prep barrier (latency overlap)
    const float* base = out + ((size_t)(b * NANCH + a) * (5 + NCLS)) * HW + hw;
    const float r0 = base[0];
    const float r1 = base[HW];
    const float r2 = base[2 * HW];
    const float r3 = base[3 * HW];
    const float r4 = base[4 * HW];

    if (tid < 64)
        prep_targets(target, b, tid, s_gx, s_gy, s_gw, s_gh, s_box, s_gam, s_meta);
    __syncthreads();

    const float sx = __builtin_amdgcn_rcpf(1.0f + __expf(-r0));
    const float sy = __builtin_amdgcn_rcpf(1.0f + __expf(-r1));

    // reference's anchor-broadcast quirk: effective anchor = (3b+a)//16
    const int aidx = (3 * b + a) >> 4;
    const float aw = aidx == 0 ? AW0 : (aidx == 1 ? AW1 : AW2);
    const float ah = aidx == 0 ? AH0 : (aidx == 1 ? AH1 : AH2);

    const float px = sx + (float)w;
    const float py = sy + (float)h;
    const float pw = __expf(r2) * aw;
    const float ph = __expf(r3) * ah;
    const float parea = pw * ph;

    const float hx0 = px - pw * 0.5f, hx1 = px + pw * 0.5f;
    const float hy0 = py - ph * 0.5f, hy1 = py + ph * 0.5f;

    const int key = (1 << 15) | (a << 12) | (h << 6) | w;

    float curmax = 0.0f;
    int   tlast  = -1;
    #pragma unroll 5
    for (int t = 0; t < NTT; ++t) {
        const float4 bx  = s_box[t];
        const float2 gam = s_gam[t];
        // intersection extents: min(hi) - max(lo); invalid targets have inf box -> carea 0
        const float cw = fminf(hx1, bx.y) - fmaxf(hx0, bx.x);
        const float ch = fminf(hy1, bx.w) - fmaxf(hy0, bx.z);
        const float carea = (cw <= 0.0f || ch <= 0.0f) ? 0.0f : cw * ch;
        const float uarea = parea + gam.x - carea;
        curmax = fmaxf(curmax, carea * __builtin_amdgcn_rcpf(uarea));
        if (__float_as_int(gam.y) == key) tlast = t;  // key has valid bit; last valid t wins
    }

    const float conf = __builtin_amdgcn_rcpf(1.0f + __expf(-r4));
    float lsum;
    if (tlast >= 0) {
        const int best = (s_meta[tlast] >> 12) & 3;
        const float baw = best == 0 ? AW0 : (best == 1 ? AW1 : AW2);
        const float bah = best == 0 ? AH0 : (best == 1 ? AH1 : AH2);
        const float tx = s_gx[tlast] - (float)w;
        const float ty = s_gy[tlast] - (float)h;
        const float tw = __logf(s_gw[tlast] * __builtin_amdgcn_rcpf(baw));
        const float th = __logf(s_gh[tlast] * __builtin_amdgcn_rcpf(bah));

        const float dx = sx - tx, dy = sy - ty, dw = r2 - tw, dh = r3 - th;
        const float dc = conf - 1.0f;
        lsum = dc * dc + 0.5f * (dx * dx + dy * dy + dw * dw + dh * dh);
    } else {
        lsum = (curmax > 0.5f) ? 0.0f : conf * conf;
    }

    // ===== merged target-NLL: first 13 blocks of each batch host one target per wave =====
    if (sub < 13) {
        const int t = sub * 4 + wid;            // 52 wave-slots >= 50 targets
        if (t < NTT) {
            const int m = s_meta[t];            // wave-uniform
            if (m != 0) {
                // "last valid t wins": skip if any later t has the same cell key
                const int mv_lane = (lane < NTT) ? s_meta[lane] : 0;
                const unsigned long long dup = __ballot(lane > t && mv_lane == m);
                if (dup == 0ULL) {
                    const int best = (m >> 12) & 3;
                    const int thw  = m & 0xFFF;
                    const float* cb = out + ((size_t)(b * NANCH + best) * (5 + NCLS) + 5) * HW + thw;

                    const float l0 = cb[lane * HW];
                    const float l1 = (lane < NCLS - 64) ? cb[(lane + 64) * HW] : -INFINITY;

                    float mx = fmaxf(l0, l1);
                    #pragma unroll
                    for (int off = 32; off > 0; off >>= 1)
                        mx = fmaxf(mx, __shfl_xor(mx, off, 64));

                    float e = __expf(l0 - mx) + ((lane < NCLS - 64) ? __expf(l1 - mx) : 0.0f);
                    #pragma unroll
                    for (int off = 32; off > 0; off >>= 1)
                        e += __shfl_xor(e, off, 64);

                    if (lane == 0) {
                        const int tc = (int)target[b * (NTT * 5) + t * 5];
                        const float lt = cb[tc * HW];
                        lsum += -(lt - mx - __logf(e));
                    }
                }
            }
        }
    }

    // reduce: wave shuffle -> LDS -> one partial store per block (no atomics)
    float v = lsum;
    #pragma unroll
    for (int off = 32; off > 0; off >>= 1) v += __shfl_down(v, off, 64);
    if (lane == 0) s_part[wid] = v;
    __syncthreads();
    if (tid == 0)
        partials[cblk] = s_part[0] + s_part[1] + s_part[2] + s_part[3];
}

__global__ __launch_bounds__(256) void yolo_reduce_kernel(
    const float* __restrict__ partials, float* __restrict__ loss)
{
    __shared__ float s_part[4];
    const int tid = threadIdx.x;
    float v = partials[tid] + partials[tid + 256] + partials[tid + 512];
    #pragma unroll
    for (int off = 32; off > 0; off >>= 1) v += __shfl_down(v, off, 64);
    const int lane = tid & 63, wid = tid >> 6;
    if (lane == 0) s_part[wid] = v;
    __syncthreads();
    if (tid == 0) loss[0] = s_part[0] + s_part[1] + s_part[2] + s_part[3];
}

extern "C" void kernel_launch(void* const* d_in, const int* in_sizes, int n_in,
                              void* d_out, int out_size, void* d_ws, size_t ws_size,
                              hipStream_t stream) {
    const float* out_t  = (const float*)d_in[0];   // (16, 255, 64, 64) f32
    const float* target = (const float*)d_in[1];   // (16, 250) f32
    float* loss     = (float*)d_out;
    float* partials = (float*)d_ws;

    yolo_loss_kernel<<<CELLBLOCKS, 256, 0, stream>>>(out_t, target, partials);
    yolo_reduce_kernel<<<1, 256, 0, stream>>>(partials, loss);
}